// Round 1
// baseline (292.773 us; speedup 1.0000x reference)
//
#include <hip/hip_runtime.h>
#include <math.h>

#define D 128
#define NNODES 10000
#define NEDGES 16384
#define PADR 136   // padded row stride (bf16 elems): +8 keeps b128 frag reads ~2-way

typedef short short8 __attribute__((ext_vector_type(8)));
typedef float floatx4 __attribute__((ext_vector_type(4)));

__device__ __forceinline__ float bf2f(unsigned short u) {
  union { unsigned u; float f; } v; v.u = ((unsigned)u) << 16; return v.f;
}
__device__ __forceinline__ unsigned short f2bf(float f) {
  union { float f; unsigned u; } v; v.f = f;
  return (unsigned short)((v.u + 0x7FFFu + ((v.u >> 16) & 1u)) >> 16);
}

// K1: h = relu(edge_attr @ w1 + b1) -> hT[k][e] bf16 (row 128 = ones),
//     gather x_j -> xjb bf16 padded rows, cnt atomics.
__global__ __launch_bounds__(256) void k1_edge(
    const float* __restrict__ x, const int* __restrict__ eidx,
    const float* __restrict__ ea, const float* __restrict__ w1,
    const float* __restrict__ b1, unsigned short* __restrict__ hT,
    unsigned short* __restrict__ xjb, float* __restrict__ cnt) {
  __shared__ __align__(16) unsigned short eaL[64 * PADR];
  __shared__ __align__(16) unsigned short w1T[D * PADR];
  __shared__ int srcL[64];
  const int t = threadIdx.x;
  const int e0 = blockIdx.x * 64;
  if (t < 64) srcL[t] = eidx[e0 + t];
  if (t >= 64 && t < 128) atomicAdd(cnt + eidx[NEDGES + e0 + (t - 64)], 1.0f);
#pragma unroll 4
  for (int r = 0; r < 32; ++r) {
    int idx = r * 256 + t, e = idx >> 7, i = idx & 127;
    eaL[e * PADR + i] = f2bf(ea[(e0 + e) * D + i]);
  }
#pragma unroll 4
  for (int r = 0; r < 64; ++r) {
    int idx = r * 256 + t, i = idx >> 7, k = idx & 127;
    w1T[k * PADR + i] = f2bf(w1[i * D + k]);
  }
  __syncthreads();
  // gather x_j rows -> xjb (bf16, padded row stride, pad left untouched/unused)
#pragma unroll 4
  for (int r = 0; r < 16; ++r) {
    int idx = r * 256 + t, e = idx >> 6, i2 = (idx & 63) * 2;
    const float2 v = *(const float2*)(x + (long)srcL[e] * D + i2);
    unsigned p = (unsigned)f2bf(v.x) | ((unsigned)f2bf(v.y) << 16);
    *(unsigned*)(xjb + ((e0 + e) * PADR + i2)) = p;
  }
  const int lane = t & 63, w = t >> 6, lo = lane & 15, hi = lane >> 4;
  floatx4 acc[8];
#pragma unroll
  for (int nt = 0; nt < 8; ++nt) acc[nt] = (floatx4){0.f, 0.f, 0.f, 0.f};
#pragma unroll
  for (int ks = 0; ks < 4; ++ks) {
    const int ib = ks * 32 + hi * 8;
    const short8 af = *(const short8*)&eaL[(w * 16 + lo) * PADR + ib];
#pragma unroll
    for (int nt = 0; nt < 8; ++nt) {
      const short8 bf_ = *(const short8*)&w1T[(nt * 16 + lo) * PADR + ib];
      acc[nt] = __builtin_amdgcn_mfma_f32_16x16x32_bf16(af, bf_, acc[nt], 0, 0, 0);
    }
  }
#pragma unroll
  for (int nt = 0; nt < 8; ++nt) {
    const int ko = nt * 16 + lo;
    const float b1v = b1[ko];
    float v0 = fmaxf(acc[nt][0] + b1v, 0.f);
    float v1 = fmaxf(acc[nt][1] + b1v, 0.f);
    float v2 = fmaxf(acc[nt][2] + b1v, 0.f);
    float v3 = fmaxf(acc[nt][3] + b1v, 0.f);
    uint2 pk;
    pk.x = (unsigned)f2bf(v0) | ((unsigned)f2bf(v1) << 16);
    pk.y = (unsigned)f2bf(v2) | ((unsigned)f2bf(v3) << 16);
    *(uint2*)(hT + (ko * NEDGES + e0 + w * 16 + hi * 4)) = pk;
  }
  if (t < 64) hT[128 * NEDGES + e0 + t] = 0x3F80;  // bf16(1.0) ones-row (b2 term)
}

// K2: w2t[k][o][i] = bf16(w2[k][i*128+o]); row 128 from b2. Padded i-stride 136.
__global__ __launch_bounds__(256) void k2_w2t(
    const float* __restrict__ w2, const float* __restrict__ b2,
    unsigned short* __restrict__ w2t) {
  __shared__ __align__(16) unsigned short L[D * PADR];
  const int t = threadIdx.x, k = blockIdx.x;
  const float* __restrict__ src = (k < D) ? (w2 + (long)k * (D * D)) : b2;
#pragma unroll 4
  for (int r = 0; r < 64; ++r) {
    int idx = r * 256 + t;
    L[(idx >> 7) * PADR + (idx & 127)] = f2bf(src[idx]);
  }
  __syncthreads();
  unsigned short* dst = w2t + (long)k * (D * PADR);
#pragma unroll 4
  for (int r = 0; r < 32; ++r) {
    int p = r * 256 + t, o = p >> 6, i2 = (p & 63) * 2;
    unsigned v = (unsigned)L[i2 * PADR + o] | ((unsigned)L[(i2 + 1) * PADR + o] << 16);
    *(unsigned*)(dst + (o * PADR + i2)) = v;
  }
}

// K3: fused per-edge matvec. Block = 64 edges x 128 outputs, k-range split in 2.
// PT[o][e] per staged w2t row k, msg += h[e,k]*PT; atomic scatter-add into seg.
__global__ __launch_bounds__(128, 2) void k3_msg(
    const unsigned short* __restrict__ w2t,
    const unsigned short* __restrict__ xjb,
    const unsigned short* __restrict__ hT,
    const int* __restrict__ eidx, float* __restrict__ seg) {
  __shared__ __align__(16) unsigned short A[D * PADR];    // 34816 B
  __shared__ __align__(16) unsigned short Xj[64 * PADR];  // 17408 B
  __shared__ __align__(16) unsigned short hL[65 * 64];    //  8320 B
  const int t = threadIdx.x;
  const int g = blockIdx.x & 255, half = blockIdx.x >> 8;
  const int e0 = g * 64;
  const int k0 = half * 65;
  const int kcnt = half ? 64 : 65;
  {
    const uint2* s = (const uint2*)(xjb + (long)e0 * PADR);
    uint2* d = (uint2*)Xj;
#pragma unroll
    for (int r = 0; r < 17; ++r) d[r * 128 + t] = s[r * 128 + t];
  }
  {
    const int tot = kcnt * 64;
    for (int r = 0; r < 33; ++r) {
      int idx = r * 128 + t;
      if (idx < tot) hL[idx] = hT[(long)(k0 + (idx >> 6)) * NEDGES + e0 + (idx & 63)];
    }
  }
  const int lane = t & 63, wv = t >> 6, lo = lane & 15, hi = lane >> 4;
  const int wo = wv * 64;  // wave's o-offset
  floatx4 msg[4][4];
#pragma unroll
  for (int mo = 0; mo < 4; ++mo)
#pragma unroll
    for (int ne = 0; ne < 4; ++ne) msg[mo][ne] = (floatx4){0.f, 0.f, 0.f, 0.f};

  for (int krel = 0; krel < kcnt; ++krel) {
    __syncthreads();  // previous compute done; fills visible on first iter
    {
      const uint4* gs = (const uint4*)(w2t + (long)(k0 + krel) * (D * PADR));
      uint4* al = (uint4*)A;
#pragma unroll
      for (int r = 0; r < 17; ++r) al[r * 128 + t] = gs[r * 128 + t];
    }
    __syncthreads();  // A staged
    float hk[4];
#pragma unroll
    for (int ne = 0; ne < 4; ++ne) hk[ne] = bf2f(hL[krel * 64 + ne * 16 + lo]);
    floatx4 P[4][4];
#pragma unroll
    for (int mo = 0; mo < 4; ++mo)
#pragma unroll
      for (int ne = 0; ne < 4; ++ne) P[mo][ne] = (floatx4){0.f, 0.f, 0.f, 0.f};
#pragma unroll
    for (int ks = 0; ks < 4; ++ks) {
      const int ib = ks * 32 + hi * 8;
      short8 af[4], bfr[4];
#pragma unroll
      for (int mo = 0; mo < 4; ++mo)
        af[mo] = *(const short8*)&A[(wo + mo * 16 + lo) * PADR + ib];
#pragma unroll
      for (int ne = 0; ne < 4; ++ne)
        bfr[ne] = *(const short8*)&Xj[(ne * 16 + lo) * PADR + ib];
#pragma unroll
      for (int mo = 0; mo < 4; ++mo)
#pragma unroll
        for (int ne = 0; ne < 4; ++ne)
          P[mo][ne] = __builtin_amdgcn_mfma_f32_16x16x32_bf16(af[mo], bfr[ne], P[mo][ne], 0, 0, 0);
    }
#pragma unroll
    for (int mo = 0; mo < 4; ++mo)
#pragma unroll
      for (int ne = 0; ne < 4; ++ne)
#pragma unroll
        for (int r = 0; r < 4; ++r)
          msg[mo][ne][r] += hk[ne] * P[mo][ne][r];
  }
  // scatter-add: D[o][e], col e = lane&15 (+16*ne), row o = wo + mo*16 + hi*4 + r
#pragma unroll
  for (int ne = 0; ne < 4; ++ne) {
    const int node = eidx[NEDGES + e0 + ne * 16 + lo];
    float* base = seg + (long)node * D + wo + hi * 4;
#pragma unroll
    for (int mo = 0; mo < 4; ++mo)
#pragma unroll
      for (int r = 0; r < 4; ++r)
        atomicAdd(base + mo * 16 + r, msg[mo][ne][r]);
  }
}

// K4: out = x + gelu(seg/max(cnt,1) + x@root + bias)
__global__ __launch_bounds__(256) void k4_out(
    const float* __restrict__ x, const float* __restrict__ root,
    const float* __restrict__ bias, const float* __restrict__ seg,
    const float* __restrict__ cnt, float* __restrict__ out) {
  __shared__ __align__(16) unsigned short xL[64 * PADR];
  __shared__ __align__(16) unsigned short rT[D * PADR];
  const int t = threadIdx.x;
  const int n0 = blockIdx.x * 64;
#pragma unroll 4
  for (int r = 0; r < 32; ++r) {
    int idx = r * 256 + t, n = idx >> 7, i = idx & 127;
    float v = (n0 + n < NNODES) ? x[(long)(n0 + n) * D + i] : 0.f;
    xL[n * PADR + i] = f2bf(v);
  }
#pragma unroll 4
  for (int r = 0; r < 64; ++r) {
    int idx = r * 256 + t, ci = idx >> 7, co = idx & 127;
    rT[co * PADR + ci] = f2bf(root[ci * D + co]);
  }
  __syncthreads();
  const int lane = t & 63, w = t >> 6, lo = lane & 15, hi = lane >> 4;
  floatx4 acc[8];
#pragma unroll
  for (int nt = 0; nt < 8; ++nt) acc[nt] = (floatx4){0.f, 0.f, 0.f, 0.f};
#pragma unroll
  for (int ks = 0; ks < 4; ++ks) {
    const int ib = ks * 32 + hi * 8;
    const short8 af = *(const short8*)&xL[(w * 16 + lo) * PADR + ib];
#pragma unroll
    for (int nt = 0; nt < 8; ++nt) {
      const short8 bf_ = *(const short8*)&rT[(nt * 16 + lo) * PADR + ib];
      acc[nt] = __builtin_amdgcn_mfma_f32_16x16x32_bf16(af, bf_, acc[nt], 0, 0, 0);
    }
  }
#pragma unroll
  for (int nt = 0; nt < 8; ++nt) {
    const int co = nt * 16 + lo;
    const float bv = bias[co];
#pragma unroll
    for (int r = 0; r < 4; ++r) {
      const int n = n0 + w * 16 + hi * 4 + r;
      if (n < NNODES) {
        const float aggr = seg[(long)n * D + co] / fmaxf(cnt[n], 1.0f);
        const float v = acc[nt][r] + aggr + bv;
        const float ge = 0.5f * v * (1.0f + erff(v * 0.70710678f));
        out[(long)n * D + co] = x[(long)n * D + co] + ge;
      }
    }
  }
}

extern "C" void kernel_launch(void* const* d_in, const int* in_sizes, int n_in,
                              void* d_out, int out_size, void* d_ws, size_t ws_size,
                              hipStream_t stream) {
  (void)in_sizes; (void)n_in; (void)out_size; (void)ws_size;
  const float* x    = (const float*)d_in[0];
  const int*   eidx = (const int*)d_in[1];
  const float* ea   = (const float*)d_in[2];
  const float* w1   = (const float*)d_in[3];
  const float* b1   = (const float*)d_in[4];
  const float* w2   = (const float*)d_in[5];
  const float* b2   = (const float*)d_in[6];
  const float* root = (const float*)d_in[7];
  const float* bias = (const float*)d_in[8];
  float* out = (float*)d_out;
  char* ws = (char*)d_ws;
  // ws layout (bytes):
  //   hT  : 129*16384 bf16          = 4,227,072   @ 0
  //   xjb : 16384*136 bf16          = 4,456,448   @ 4,227,072
  //   w2t : 129*128*136 bf16        = 4,491,264   @ 8,683,520
  //   seg : 10000*128 f32           = 5,120,000   @ 13,174,784
  //   cnt : 10000 f32               =    40,000   @ 18,294,784   (total 18.3 MB)
  unsigned short* hT  = (unsigned short*)(ws + 0);
  unsigned short* xjb = (unsigned short*)(ws + 4227072);
  unsigned short* w2t = (unsigned short*)(ws + 8683520);
  float* seg = (float*)(ws + 13174784);
  float* cnt = (float*)(ws + 18294784);
  hipMemsetAsync(ws + 13174784, 0, 5160000, stream);  // seg + cnt
  hipLaunchKernelGGL(k1_edge, dim3(NEDGES / 64), dim3(256), 0, stream,
                     x, eidx, ea, w1, b1, hT, xjb, cnt);
  hipLaunchKernelGGL(k2_w2t, dim3(129), dim3(256), 0, stream, w2, b2, w2t);
  hipLaunchKernelGGL(k3_msg, dim3(512), dim3(128), 0, stream,
                     w2t, xjb, hT, eidx, seg);
  hipLaunchKernelGGL(k4_out, dim3((NNODES + 63) / 64), dim3(256), 0, stream,
                     x, root, bias, seg, cnt, out);
}